// Round 4
// baseline (365.641 us; speedup 1.0000x reference)
//
#include <hip/hip_runtime.h>
#include <math.h>

// Problem constants (fixed by reference setup_inputs)
#define NQ    2048      // B*QB
#define Dd    256
#define NHh   8
#define HDd   32
#define KK    164       // 9+25+49+81
#define KP    192       // padded K (6 full 32-tiles)
#define PPB   5440      // valid cells per batch: 64+256+1024+4096
#define M_TOT 21760     // 4 * PPB
#define TWO_D 512

using bf16x8 = __attribute__((ext_vector_type(8))) short;
using f32x4  = __attribute__((ext_vector_type(4))) float;

__device__ __forceinline__ unsigned short bf16_rne(float x) {
    unsigned u = __float_as_uint(x);
    return (unsigned short)((u + 0x7fffu + ((u >> 16) & 1u)) >> 16);
}

__device__ __forceinline__ void gload_lds16(const void* g, void* s) {
    __builtin_amdgcn_global_load_lds(
        (const __attribute__((address_space(1))) void*)g,
        (__attribute__((address_space(3))) void*)s, 16, 0, 0);
}

__device__ __forceinline__ void row_geom(int r, int& l, int& S, int& base, int& lg, int& inv) {
    if      (r < 64)   { l = 0; S = 8;  base = 0;    lg = 3; inv = 8; }
    else if (r < 320)  { l = 1; S = 16; base = 64;   lg = 4; inv = 4; }
    else if (r < 1344) { l = 2; S = 32; base = 320;  lg = 5; inv = 2; }
    else               { l = 3; S = 64; base = 1344; lg = 6; inv = 1; }
}

// ---------------------------------------------------------------------------
// gather valid cells, split fp32 -> bf16 hi/lo, compacted [m][k=256]
// ---------------------------------------------------------------------------
__global__ __launch_bounds__(256) void gather_split(const float* __restrict__ fmap,
                                                    unsigned short* __restrict__ Ahi,
                                                    unsigned short* __restrict__ Alo) {
    int gid = blockIdx.x * 256 + threadIdx.x;
    int m = gid >> 6, c4 = (gid & 63) << 2;
    int b = m / PPB, r = m - b * PPB;
    int l, S, base, lg, inv;
    row_geom(r, l, S, base, lg, inv);
    int idx = r - base;
    int i = idx >> lg, j = idx & (S - 1);
    size_t rowOff = ((size_t)((b * 64 + i) * 64 + j)) * 1024 + l * 256;
    const float4 v = *(const float4*)(fmap + rowOff + c4);
    ushort4 hi, lo;
    hi.x = bf16_rne(v.x); lo.x = bf16_rne(v.x - __uint_as_float((unsigned)hi.x << 16));
    hi.y = bf16_rne(v.y); lo.y = bf16_rne(v.y - __uint_as_float((unsigned)hi.y << 16));
    hi.z = bf16_rne(v.z); lo.z = bf16_rne(v.z - __uint_as_float((unsigned)hi.z << 16));
    hi.w = bf16_rne(v.w); lo.w = bf16_rne(v.w - __uint_as_float((unsigned)hi.w << 16));
    *(ushort4*)(Ahi + (size_t)m * 256 + c4) = hi;
    *(ushort4*)(Alo + (size_t)m * 256 + c4) = lo;
}

// ---------------------------------------------------------------------------
// W (256 x N, row-major over k) -> Bt hi/lo transposed [n][k=256]
// ---------------------------------------------------------------------------
__global__ __launch_bounds__(256) void splitw_t(const float* __restrict__ W,
                                                unsigned short* __restrict__ Bthi,
                                                unsigned short* __restrict__ Btlo,
                                                int N) {
    int gid = blockIdx.x * 256 + threadIdx.x;
    int k = gid & 255, n = gid >> 8;
    float x = W[k * N + n];
    unsigned short h = bf16_rne(x);
    unsigned short lo = bf16_rne(x - __uint_as_float((unsigned)h << 16));
    Bthi[n * 256 + k] = h;
    Btlo[n * 256 + k] = lo;
}

// ---------------------------------------------------------------------------
// KV = A @ Wkv via split-bf16 MFMA (M=21760, N=512, K=256, 3 segments).
// 128x128 tile, 2x2 waves, 4x4 frags of 16x16x32.
// Swizzle v2: 16B-slot key (row>>1)&3  -> 2-way (free) LDS reads.
// ---------------------------------------------------------------------------
__global__ __launch_bounds__(256) void kv_gemm_mfma(const unsigned short* __restrict__ Ahi,
                                                    const unsigned short* __restrict__ Alo,
                                                    const unsigned short* __restrict__ Bthi,
                                                    const unsigned short* __restrict__ Btlo,
                                                    float* __restrict__ kvws) {
    __shared__ __align__(16) short As[2][128 * 32];
    __shared__ __align__(16) short Bs[2][128 * 32];

    const int t  = threadIdx.x;
    const int w  = t >> 6, l = t & 63;
    const int wr = w >> 1, wc = w & 1;
    const int bm = blockIdx.x * 128, n0 = blockIdx.y * 128;
    const int lr = l & 15, ks = l >> 4;
    const int ksw8 = ((ks ^ ((lr >> 1) & 3)) << 3);

    f32x4 acc[4][4];
#pragma unroll
    for (int i = 0; i < 4; i++)
#pragma unroll
        for (int j = 0; j < 4; j++) { f32x4 z = {0.f,0.f,0.f,0.f}; acc[i][j] = z; }

    const int srow = l >> 2, sslot = l & 3;
    const int gs = sslot ^ ((srow >> 1) & 3);   // pre-swizzled global slot

    auto stage = [&](int kt, int buf) {
        int seg = kt >> 3;
        const unsigned short* Aseg = (seg < 2) ? Ahi : Alo;
        const unsigned short* Bseg = (seg == 1) ? Btlo : Bthi;
        size_t k0b = (size_t)((kt & 7) << 6);
#pragma unroll
        for (int i = 0; i < 2; i++) {
            int rb = w * 32 + i * 16;
            int m  = rb + srow;
            gload_lds16((const char*)Aseg + (((size_t)(bm + m)) << 9) + k0b + (gs << 4),
                        (void*)&As[buf][rb * 32]);
            gload_lds16((const char*)Bseg + (((size_t)(n0 + m)) << 9) + k0b + (gs << 4),
                        (void*)&Bs[buf][rb * 32]);
        }
    };

    stage(0, 0);
    __syncthreads();

    for (int kt = 0; kt < 24; kt++) {
        int cur = kt & 1;
        if (kt < 23) stage(kt + 1, cur ^ 1);

        bf16x8 afr[4], bfr[4];
#pragma unroll
        for (int f = 0; f < 4; f++) {
            int m = wr * 64 + f * 16 + lr;
            afr[f] = *(const bf16x8*)&As[cur][m * 32 + ksw8];
            int n = wc * 64 + f * 16 + lr;
            bfr[f] = *(const bf16x8*)&Bs[cur][n * 32 + ksw8];
        }
#pragma unroll
        for (int i = 0; i < 4; i++)
#pragma unroll
            for (int j = 0; j < 4; j++)
                acc[i][j] = __builtin_amdgcn_mfma_f32_16x16x32_bf16(afr[i], bfr[j],
                                                                    acc[i][j], 0, 0, 0);
        __syncthreads();
    }

#pragma unroll
    for (int i = 0; i < 4; i++) {
        int mg = bm + wr * 64 + i * 16 + ks * 4;
#pragma unroll
        for (int j = 0; j < 4; j++) {
            int ng = n0 + wc * 64 + j * 16 + lr;
#pragma unroll
            for (int r = 0; r < 4; r++)
                kvws[(size_t)(mg + r) * TWO_D + ng] = acc[i][j][r];
        }
    }
}

// ---------------------------------------------------------------------------
// proj GEMM: C(2048x256) = A(2048x256) @ W(256x256) [+resid], split-bf16 MFMA
// BM=128, BN=64; 4 waves stacked on M; 2x4 frags each.
// ---------------------------------------------------------------------------
template<bool RESID>
__global__ __launch_bounds__(256) void proj_gemm(const unsigned short* __restrict__ Ahi,
                                                 const unsigned short* __restrict__ Alo,
                                                 const unsigned short* __restrict__ Bthi,
                                                 const unsigned short* __restrict__ Btlo,
                                                 float* __restrict__ C,
                                                 const float* __restrict__ resid) {
    __shared__ __align__(16) short As[2][128 * 32];
    __shared__ __align__(16) short Bs[2][64 * 32];

    const int t  = threadIdx.x;
    const int w  = t >> 6, l = t & 63;
    const int bm = blockIdx.x * 128, n0 = blockIdx.y * 64;
    const int lr = l & 15, ks = l >> 4;
    const int ksw8 = ((ks ^ ((lr >> 1) & 3)) << 3);

    f32x4 acc[2][4];
#pragma unroll
    for (int i = 0; i < 2; i++)
#pragma unroll
        for (int j = 0; j < 4; j++) { f32x4 z = {0.f,0.f,0.f,0.f}; acc[i][j] = z; }

    const int srow = l >> 2, sslot = l & 3;
    const int gs = sslot ^ ((srow >> 1) & 3);

    auto stage = [&](int kt, int buf) {
        int seg = kt >> 3;
        const unsigned short* Aseg = (seg < 2) ? Ahi : Alo;
        const unsigned short* Bseg = (seg == 1) ? Btlo : Bthi;
        size_t k0b = (size_t)((kt & 7) << 6);
#pragma unroll
        for (int i = 0; i < 2; i++) {
            int rb = w * 32 + i * 16;
            int m  = rb + srow;
            gload_lds16((const char*)Aseg + (((size_t)(bm + m)) << 9) + k0b + (gs << 4),
                        (void*)&As[buf][rb * 32]);
        }
        {
            int rb = w * 16;
            int m  = rb + srow;
            gload_lds16((const char*)Bseg + (((size_t)(n0 + m)) << 9) + k0b + (gs << 4),
                        (void*)&Bs[buf][rb * 32]);
        }
    };

    stage(0, 0);
    __syncthreads();

    for (int kt = 0; kt < 24; kt++) {
        int cur = kt & 1;
        if (kt < 23) stage(kt + 1, cur ^ 1);

        bf16x8 afr[2], bfr[4];
#pragma unroll
        for (int f = 0; f < 2; f++) {
            int m = w * 32 + f * 16 + lr;
            afr[f] = *(const bf16x8*)&As[cur][m * 32 + ksw8];
        }
#pragma unroll
        for (int j = 0; j < 4; j++) {
            int n = j * 16 + lr;
            bfr[j] = *(const bf16x8*)&Bs[cur][n * 32 + ksw8];
        }
#pragma unroll
        for (int i = 0; i < 2; i++)
#pragma unroll
            for (int j = 0; j < 4; j++)
                acc[i][j] = __builtin_amdgcn_mfma_f32_16x16x32_bf16(afr[i], bfr[j],
                                                                    acc[i][j], 0, 0, 0);
        __syncthreads();
    }

#pragma unroll
    for (int i = 0; i < 2; i++) {
        int mg = bm + w * 32 + i * 16 + ks * 4;
#pragma unroll
        for (int j = 0; j < 4; j++) {
            int ng = n0 + j * 16 + lr;
#pragma unroll
            for (int r = 0; r < 4; r++) {
                float v = acc[i][j][r];
                if (RESID) v += resid[(size_t)(mg + r) * 256 + ng];
                C[(size_t)(mg + r) * 256 + ng] = v;
            }
        }
    }
}

// ---------------------------------------------------------------------------
// in-place RoPE on the K half of kvws (key_pos is cell-determined)
// ---------------------------------------------------------------------------
__global__ __launch_bounds__(256) void rope_k(float* __restrict__ kvws,
                                              const float* __restrict__ freqs) {
    int gid = blockIdx.x * 256 + threadIdx.x;
    int m = gid >> 7;
    int p = gid & 127;
    int f = p & 15;

    int b = m / PPB;
    int r = m - b * PPB;
    int l, S, base, lg, inv;
    row_geom(r, l, S, base, lg, inv);
    int idx = r - base;
    int i = idx >> lg;
    int j = idx & (S - 1);

    float px = (float)(i * inv), py = (float)(j * inv), pl = (float)l;
    float ang = px * freqs[f] + py * freqs[16 + f] + pl * freqs[32 + f];
    float c = cosf(ang), s = sinf(ang);

    float2* kp = (float2*)kvws + (size_t)m * 256 + p;
    float2 v = *kp;
    *kp = make_float2(v.x * c - v.y * s, v.x * s + v.y * c);
}

// ---------------------------------------------------------------------------
// LayerNorm + bf16 hi/lo split: X = LN(query) -> Xhi/Xlo (2048 x 256)
// ---------------------------------------------------------------------------
__global__ __launch_bounds__(256) void ln_split(const float* __restrict__ query,
                                                const float* __restrict__ gamma,
                                                const float* __restrict__ beta,
                                                unsigned short* __restrict__ Xhi,
                                                unsigned short* __restrict__ Xlo) {
    __shared__ float red[4];
    const int q = blockIdx.x, t = threadIdx.x, wid = t >> 6;

    float x = query[q * Dd + t];
    float s = x;
#pragma unroll
    for (int mK = 32; mK >= 1; mK >>= 1) s += __shfl_xor(s, mK);
    if ((t & 63) == 0) red[wid] = s;
    __syncthreads();
    float mu = (red[0] + red[1] + red[2] + red[3]) * (1.0f / 256.0f);
    float dx = x - mu;
    float s2 = dx * dx;
#pragma unroll
    for (int mK = 32; mK >= 1; mK >>= 1) s2 += __shfl_xor(s2, mK);
    __syncthreads();
    if ((t & 63) == 0) red[wid] = s2;
    __syncthreads();
    float var = (red[0] + red[1] + red[2] + red[3]) * (1.0f / 256.0f);
    float v = dx * rsqrtf(var + 1e-5f) * gamma[t] + beta[t];
    unsigned short hi = bf16_rne(v);
    Xhi[q * Dd + t] = hi;
    Xlo[q * Dd + t] = bf16_rne(v - __uint_as_float((unsigned)hi << 16));
}

// ---------------------------------------------------------------------------
// RoPE on q (in place on qr, 2048 x 256 f32); pos = (qx, qy, 3)
// ---------------------------------------------------------------------------
__global__ __launch_bounds__(256) void rope_q(float* __restrict__ qr,
                                              const float* __restrict__ qpos,
                                              const float* __restrict__ freqs) {
    int gid = blockIdx.x * 256 + threadIdx.x;   // 2048*128
    int m = gid >> 7, p = gid & 127, f = p & 15;
    float qx = qpos[m * 4 + 1], qy = qpos[m * 4 + 2];
    float ang = qx * freqs[f] + qy * freqs[16 + f] + 3.0f * freqs[32 + f];
    float c = cosf(ang), s = sinf(ang);
    float2* xp = (float2*)qr + (size_t)m * 128 + p;
    float2 v = *xp;
    *xp = make_float2(v.x * c - v.y * s, v.x * s + v.y * c);
}

// ---------------------------------------------------------------------------
// attention core: scores -> softmax -> PV. One block per query.
// scores: thread (h, lane) owns 6 k's (8x float4 dots).
// PV: wave = k-chunk (48 k's), lane = (head, d-quad); float4 accumulate;
//     LDS reduce over 4 chunks. Output written as bf16 hi/lo (A of out-proj).
// ---------------------------------------------------------------------------
__global__ __launch_bounds__(256) void attn_core(const float* __restrict__ qr,
                                                 const float* __restrict__ qpos,
                                                 const float* __restrict__ kvws,
                                                 unsigned short* __restrict__ Phi,
                                                 unsigned short* __restrict__ Plo) {
    __shared__ __align__(16) float qsh[Dd];
    __shared__ float sL[NHh * KP];
    __shared__ int   kidx[KP];
    __shared__ float attnP[4][Dd];
    __shared__ float invS[NHh];

    const int q = blockIdx.x;
    const int t = threadIdx.x;
    const int h = t >> 5, lane = t & 31;

    qsh[t] = qr[q * Dd + t];

    float qx = qpos[q * 4 + 1];
    float qy = qpos[q * 4 + 2];
    int   bb = (int)qpos[q * 4 + 0];

    if (t < KP) {
        int k = t;
        int kv = -1;
        if (k < KK) {
            int S, base, off, sz, half, lg;
            if      (k < 9)  { S = 8;  base = 0;    off = k;      sz = 3; half = 1; lg = 3; }
            else if (k < 34) { S = 16; base = 64;   off = k - 9;  sz = 5; half = 2; lg = 4; }
            else if (k < 83) { S = 32; base = 320;  off = k - 34; sz = 7; half = 3; lg = 5; }
            else             { S = 64; base = 1344; off = k - 83; sz = 9; half = 4; lg = 6; }
            int di = off / sz - half;
            int dj = off % sz - half;
            float scal = (float)S * (1.0f / 64.0f);
            int ci = (int)floorf(qx * scal);
            int cj = (int)floorf(qy * scal);
            int i = ci + di, j = cj + dj;
            bool valid = (i >= 0) & (i < S) & (j >= 0) & (j < S);
            kv = valid ? (bb * PPB + base + (i << lg) + j) : -1;
        }
        kidx[t] = kv;
    }
    __syncthreads();

    // ---- scores ----
    float4 qv[8];
    {
        const float4* qp = (const float4*)(qsh + h * HDd);
#pragma unroll
        for (int i = 0; i < 8; i++) qv[i] = qp[i];
    }
#pragma unroll
    for (int ct = 0; ct < 6; ++ct) {
        int k = ct * 32 + lane;
        int ki = kidx[k];
        int kr = ki < 0 ? 0 : ki;
        const float4* kp = (const float4*)(kvws + (size_t)kr * TWO_D + h * HDd);
        float c0 = 0.f, c1 = 0.f;
#pragma unroll
        for (int i = 0; i < 8; i += 2) {
            float4 k0v = kp[i], k1v = kp[i + 1];
            c0 = fmaf(qv[i].x, k0v.x, c0); c0 = fmaf(qv[i].y, k0v.y, c0);
            c0 = fmaf(qv[i].z, k0v.z, c0); c0 = fmaf(qv[i].w, k0v.w, c0);
            c1 = fmaf(qv[i + 1].x, k1v.x, c1); c1 = fmaf(qv[i + 1].y, k1v.y, c1);
            c1 = fmaf(qv[i + 1].z, k1v.z, c1); c1 = fmaf(qv[i + 1].w, k1v.w, c1);
        }
        sL[h * KP + k] = (ki >= 0) ? (c0 + c1) : -INFINITY;
    }
    __syncthreads();

    // ---- softmax per head (32 lanes x 6 strided) ----
    float mx = -INFINITY;
#pragma unroll
    for (int ct = 0; ct < 6; ++ct) mx = fmaxf(mx, sL[h * KP + ct * 32 + lane]);
#pragma unroll
    for (int mK = 16; mK >= 1; mK >>= 1) mx = fmaxf(mx, __shfl_xor(mx, mK));
    float se = 0.f;
#pragma unroll
    for (int ct = 0; ct < 6; ++ct) {
        int k = ct * 32 + lane;
        float e = __expf(sL[h * KP + k] - mx);
        sL[h * KP + k] = e;
        se += e;
    }
#pragma unroll
    for (int mK = 16; mK >= 1; mK >>= 1) se += __shfl_xor(se, mK);
    if (lane == 0) invS[h] = 1.0f / se;
    __syncthreads();

    // ---- PV: wave rep owns k in [rep*48, rep*48+48); lane = (hh, dq) ----
    {
        const int rep = t >> 6;
        const int hh  = (t & 63) >> 3;
        const int dq  = t & 7;
        f32x4 a0 = {0.f,0.f,0.f,0.f}, a1 = {0.f,0.f,0.f,0.f};
        const float* vbase = kvws + 256 + hh * HDd + dq * 4;
#pragma unroll 4
        for (int kk = 0; kk < 24; kk++) {
            int k  = rep * 48 + kk * 2;
            int k2 = k + 1;
            float w0 = sL[hh * KP + k];
            float w1 = sL[hh * KP + k2];
            int kr0 = kidx[k];  kr0 = kr0 < 0 ? 0 : kr0;
            int kr1 = kidx[k2]; kr1 = kr1 < 0 ? 0 : kr1;
            const f32x4 v0 = *(const f32x4*)(vbase + (size_t)kr0 * TWO_D);
            const f32x4 v1 = *(const f32x4*)(vbase + (size_t)kr1 * TWO_D);
            a0 += w0 * v0;
            a1 += w1 * v1;
        }
        a0 += a1;
        float* dst = &attnP[rep][hh * HDd + dq * 4];
        dst[0] = a0[0]; dst[1] = a0[1]; dst[2] = a0[2]; dst[3] = a0[3];
    }
    __syncthreads();

    // ---- reduce 4 chunks, scale, write bf16 hi/lo ----
    float val = (attnP[0][t] + attnP[1][t] + attnP[2][t] + attnP[3][t]) * invS[h];
    unsigned short hi = bf16_rne(val);
    Phi[q * Dd + t] = hi;
    Plo[q * Dd + t] = bf16_rne(val - __uint_as_float((unsigned)hi << 16));
}

// ---------------------------------------------------------------------------
// Fallback fp32 GEMM + fused attention (round-3 versions) if ws too small
// ---------------------------------------------------------------------------
#define BMf 128
#define BNf 128
#define KTf 16

__global__ __launch_bounds__(256) void kv_gemm(const float* __restrict__ fmap,
                                               const float* __restrict__ Wkv,
                                               float* __restrict__ kvws) {
    __shared__ float Asf[KTf][BMf + 4];
    __shared__ float Bsf[KTf][BNf + 4];
    __shared__ int   rowOff[BMf];

    const int t  = threadIdx.x;
    const int bm = blockIdx.x * BMf;
    const int n0 = blockIdx.y * BNf;

    if (t < BMf) {
        int m = bm + t;
        int b = m / PPB;
        int r = m - b * PPB;
        int l, S, base, lg, inv;
        row_geom(r, l, S, base, lg, inv);
        int idx = r - base;
        int i = idx >> lg;
        int j = idx & (S - 1);
        rowOff[t] = ((b * 64 + i) * 64 + j) * 1024 + l * 256;
    }
    __syncthreads();

    const int tx = t & 15, ty = t >> 4;
    float acc[8][8];
#pragma unroll
    for (int i = 0; i < 8; i++)
#pragma unroll
        for (int j = 0; j < 8; j++) acc[i][j] = 0.f;

    for (int k0 = 0; k0 < Dd; k0 += KTf) {
#pragma unroll
        for (int s = 0; s < 2; s++) {
            int task = t + s * 256;
            int row  = task >> 2;
            int k4   = (task & 3) * 4;
            const float4 v = *(const float4*)(fmap + rowOff[row] + k0 + k4);
            Asf[k4 + 0][row] = v.x;
            Asf[k4 + 1][row] = v.y;
            Asf[k4 + 2][row] = v.z;
            Asf[k4 + 3][row] = v.w;
        }
#pragma unroll
        for (int s = 0; s < 2; s++) {
            int task = t + s * 256;
            int kk   = task >> 5;
            int c4   = (task & 31) * 4;
            *(float4*)(&Bsf[kk][c4]) = *(const float4*)(Wkv + (k0 + kk) * TWO_D + n0 + c4);
        }
        __syncthreads();
#pragma unroll
        for (int kk = 0; kk < KTf; kk++) {
            float a[8], bb[8];
#pragma unroll
            for (int i = 0; i < 8; i++) a[i]  = Asf[kk][ty * 8 + i];
#pragma unroll
            for (int j = 0; j < 8; j++) bb[j] = Bsf[kk][tx * 8 + j];
#pragma unroll
            for (int i = 0; i < 8; i++)
#pragma unroll
                for (int j = 0; j < 8; j++)
                    acc[i][j] = fmaf(a[i], bb[j], acc[i][j]);
        }
        __syncthreads();
    }

#pragma unroll
    for (int i = 0; i < 8; i++) {
        int m = bm + ty * 8 + i;
        float* dst = kvws + (size_t)m * TWO_D + n0 + tx * 8;
#pragma unroll
        for (int j = 0; j < 8; j += 4) {
            *(float4*)(dst + j) = make_float4(acc[i][j], acc[i][j + 1],
                                              acc[i][j + 2], acc[i][j + 3]);
        }
    }
}

__global__ __launch_bounds__(256) void attn_fused(const float* __restrict__ query,
                                                  const float* __restrict__ qpos,
                                                  const float* __restrict__ Wq,
                                                  const float* __restrict__ Wout,
                                                  const float* __restrict__ gamma,
                                                  const float* __restrict__ beta,
                                                  const float* __restrict__ freqs,
                                                  const float* __restrict__ kvws,
                                                  float* __restrict__ out) {
    __shared__ float qn[Dd];
    __shared__ __align__(16) float qsh[Dd];
    __shared__ float sL[NHh * KK];
    __shared__ int   kidx[KK];
    __shared__ float attnL[Dd];
    __shared__ float red[4];
    __shared__ float invS[NHh];

    const int q = blockIdx.x;
    const int t = threadIdx.x;
    const int wid = t >> 6;
    const int h = t >> 5, lane = t & 31;

    float x = query[q * Dd + t];
    float s = x;
#pragma unroll
    for (int mK = 32; mK >= 1; mK >>= 1) s += __shfl_xor(s, mK);
    if ((t & 63) == 0) red[wid] = s;
    __syncthreads();
    float mu = (red[0] + red[1] + red[2] + red[3]) * (1.0f / 256.0f);
    float dx = x - mu;
    float s2 = dx * dx;
#pragma unroll
    for (int mK = 32; mK >= 1; mK >>= 1) s2 += __shfl_xor(s2, mK);
    __syncthreads();
    if ((t & 63) == 0) red[wid] = s2;
    __syncthreads();
    float var = (red[0] + red[1] + red[2] + red[3]) * (1.0f / 256.0f);
    float rs = rsqrtf(var + 1e-5f);
    qn[t] = dx * rs * gamma[t] + beta[t];
    __syncthreads();

    float a0 = 0.f, a1 = 0.f, a2 = 0.f, a3 = 0.f;
#pragma unroll 8
    for (int d = 0; d < Dd; d += 4) {
        a0 = fmaf(qn[d + 0], Wq[(d + 0) * Dd + t], a0);
        a1 = fmaf(qn[d + 1], Wq[(d + 1) * Dd + t], a1);
        a2 = fmaf(qn[d + 2], Wq[(d + 2) * Dd + t], a2);
        a3 = fmaf(qn[d + 3], Wq[(d + 3) * Dd + t], a3);
    }
    float acc = (a0 + a1) + (a2 + a3);

    float qx = qpos[q * 4 + 1];
    float qy = qpos[q * 4 + 2];
    int   bb = (int)qpos[q * 4 + 0];
    {
        int f = (t & 31) >> 1;
        float ang = qx * freqs[f] + qy * freqs[16 + f] + 3.0f * freqs[32 + f];
        float c = cosf(ang), sn = sinf(ang);
        float partner = __shfl_xor(acc, 1);
        bool ev = !(t & 1);
        acc = ev ? (acc * c - partner * sn) : (partner * sn + acc * c);
    }
    qsh[t] = acc;

    if (t < KK) {
        int k = t;
        int S, base, off, sz, half, lg;
        if      (k < 9)  { S = 8;  base = 0;    off = k;      sz = 3; half = 1; lg = 3; }
        else if (k < 34) { S = 16; base = 64;   off = k - 9;  sz = 5; half = 2; lg = 4; }
        else if (k < 83) { S = 32; base = 320;  off = k - 34; sz = 7; half = 3; lg = 5; }
        else             { S = 64; base = 1344; off = k - 83; sz = 9; half = 4; lg = 6; }
        int di = off / sz - half;
        int dj = off % sz - half;
        float scal = (float)S * (1.0f / 64.0f);
        int ci = (int)floorf(qx * scal);
        int cj = (int)floorf(qy * scal);
        int i = ci + di, j = cj + dj;
        bool valid = (i >= 0) & (i < S) & (j >= 0) & (j < S);
        kidx[t] = valid ? (bb * PPB + base + (i << lg) + j) : -1;
    }
    __syncthreads();

    float4 qv[8];
    {
        const float4* qp = (const float4*)(qsh + h * HDd);
#pragma unroll
        for (int i = 0; i < 8; i++) qv[i] = qp[i];
    }
#pragma unroll
    for (int ct = 0; ct < 6; ++ct) {
        int k = ct * 32 + lane;
        if (k >= KK) break;
        int ki = kidx[k];
        int kr = ki < 0 ? 0 : ki;
        const float4* kp = (const float4*)(kvws + (size_t)kr * TWO_D + h * HDd);
        float c0 = 0.f, c1 = 0.f;
#pragma unroll
        for (int i = 0; i < 8; i += 2) {
            float4 k0v = kp[i], k1v = kp[i + 1];
            c0 = fmaf(qv[i].x, k0v.x, c0); c0 = fmaf(qv[i].y, k0v.y, c0);
            c0 = fmaf(qv[i].z, k0v.z, c0); c0 = fmaf(qv[i].w, k0v.w, c0);
            c1 = fmaf(qv[i + 1].x, k1v.x, c1); c1 = fmaf(qv[i + 1].y, k1v.y, c1);
            c1 = fmaf(qv[i + 1].z, k1v.z, c1); c1 = fmaf(qv[i + 1].w, k1v.w, c1);
        }
        sL[h * KK + k] = (ki >= 0) ? (c0 + c1) : -INFINITY;
    }
    __syncthreads();

    float mx = -INFINITY;
    for (int k = lane; k < KK; k += 32) mx = fmaxf(mx, sL[h * KK + k]);
#pragma unroll
    for (int mK = 16; mK >= 1; mK >>= 1) mx = fmaxf(mx, __shfl_xor(mx, mK));
    float se = 0.f;
    for (int k = lane; k < KK; k += 32) {
        float e = expf(sL[h * KK + k] - mx);
        sL[h * KK + k] = e;
        se += e;
    }
#pragma unroll
    for (int mK = 16; mK >= 1; mK >>= 1) se += __shfl_xor(se, mK);
    if (lane == 0) invS[h] = 1.0f / se;
    __syncthreads();

    float p0 = 0.f, p1 = 0.f, p2 = 0.f, p3 = 0.f;
#pragma unroll 4
    for (int k = 0; k < 164; k += 4) {
        int ki0 = kidx[k],     kr0 = ki0 < 0 ? 0 : ki0;
        int ki1 = kidx[k + 1], kr1 = ki1 < 0 ? 0 : ki1;
        int ki2 = kidx[k + 2], kr2 = ki2 < 0 ? 0 : ki2;
        int ki3 = kidx[k + 3], kr3 = ki3 < 0 ? 0 : ki3;
        p0 = fmaf(sL[h * KK + k],     kvws[(size_t)kr0 * TWO_D + Dd + t], p0);
        p1 = fmaf(sL[h * KK + k + 1], kvws[(size_t)kr1 * TWO_D + Dd + t], p1);
        p2 = fmaf(sL[h * KK + k + 2], kvws[(size_t)kr2 * TWO_D + Dd + t], p2);
        p3 = fmaf(sL[h * KK + k + 3], kvws[(size_t)kr3 * TWO_D + Dd + t], p3);
    }
    attnL[t] = ((p0 + p1) + (p2 + p3)) * invS[h];
    __syncthreads();

    float o0 = query[q * Dd + t], o1 = 0.f, o2 = 0.f, o3 = 0.f;
#pragma unroll 8
    for (int d = 0; d < Dd; d += 4) {
        o0 = fmaf(attnL[d + 0], Wout[(d + 0) * Dd + t], o0);
        o1 = fmaf(attnL[d + 1], Wout[(d + 1) * Dd + t], o1);
        o2 = fmaf(attnL[d + 2], Wout[(d + 2) * Dd + t], o2);
        o3 = fmaf(attnL[d + 3], Wout[(d + 3) * Dd + t], o3);
    }
    out[q * Dd + t] = (o0 + o1) + (o2 + o3);
}

// ---------------------------------------------------------------------------
extern "C" void kernel_launch(void* const* d_in, const int* in_sizes, int n_in,
                              void* d_out, int out_size, void* d_ws, size_t ws_size,
                              hipStream_t stream) {
    const float* query = (const float*)d_in[0];
    const float* qpos  = (const float*)d_in[1];
    const float* fmap  = (const float*)d_in[3];
    const float* gamma = (const float*)d_in[5];
    const float* beta  = (const float*)d_in[6];
    const float* Wq    = (const float*)d_in[7];
    const float* Wkv   = (const float*)d_in[8];
    const float* Wout  = (const float*)d_in[9];
    const float* freqs = (const float*)d_in[10];
    float* out  = (float*)d_out;
    float* kvws = (float*)d_ws;

    const size_t KV_B = (size_t)M_TOT * TWO_D * 4;   // 44,564,480
    const size_t A_B  = (size_t)M_TOT * Dd * 2;      // 11,141,120
    const size_t WT_B = (size_t)Dd * TWO_D * 2;      // 262,144
    const size_t need = KV_B + 2 * A_B + 2 * WT_B;   // 67,371,008 (round-3-proven)

    if (ws_size >= need) {
        char* base = (char*)d_ws;
        unsigned short* Ahi    = (unsigned short*)(base + KV_B);
        unsigned short* Alo    = (unsigned short*)(base + KV_B + A_B);
        unsigned short* WkvThi = (unsigned short*)(base + KV_B + 2 * A_B);
        unsigned short* WkvTlo = (unsigned short*)(base + KV_B + 2 * A_B + WT_B);
        // overlay inside the Ahi region (dead after kv_gemm_mfma):
        unsigned short* Phi    = (unsigned short*)(base + KV_B);              // 1 MB (also Xhi)
        unsigned short* Plo    = (unsigned short*)(base + KV_B + 1048576);    // 1 MB (also Xlo)
        float*          qrw    = (float*)        (base + KV_B + 2097152);    // 2 MB
        unsigned short* WqThi  = (unsigned short*)(base + KV_B + 4194304);
        unsigned short* WqTlo  = (unsigned short*)(base + KV_B + 4325376);
        unsigned short* WoThi  = (unsigned short*)(base + KV_B + 4456448);
        unsigned short* WoTlo  = (unsigned short*)(base + KV_B + 4587520);

        gather_split<<<dim3((M_TOT * 64) / 256), 256, 0, stream>>>(fmap, Ahi, Alo);
        splitw_t<<<dim3(512), 256, 0, stream>>>(Wkv, WkvThi, WkvTlo, 512);
        kv_gemm_mfma<<<dim3(M_TOT / 128, 4), 256, 0, stream>>>(Ahi, Alo, WkvThi, WkvTlo, kvws);
        rope_k<<<dim3((M_TOT * 128) / 256), 256, 0, stream>>>(kvws, freqs);
        // Ahi/Alo now dead -> overlay region usable
        ln_split<<<dim3(NQ), 256, 0, stream>>>(query, gamma, beta, Phi, Plo);  // X in P slots
        splitw_t<<<dim3(256), 256, 0, stream>>>(Wq, WqThi, WqTlo, 256);
        splitw_t<<<dim3(256), 256, 0, stream>>>(Wout, WoThi, WoTlo, 256);
        proj_gemm<false><<<dim3(NQ / 128, 4), 256, 0, stream>>>(Phi, Plo, WqThi, WqTlo,
                                                                qrw, nullptr);
        rope_q<<<dim3((NQ * 128) / 256), 256, 0, stream>>>(qrw, qpos, freqs);
        attn_core<<<dim3(NQ), 256, 0, stream>>>(qrw, qpos, kvws, Phi, Plo);
        proj_gemm<true><<<dim3(NQ / 128, 4), 256, 0, stream>>>(Phi, Plo, WoThi, WoTlo,
                                                               out, query);
    } else {
        kv_gemm<<<dim3(M_TOT / BMf, TWO_D / BNf), 256, 0, stream>>>(fmap, Wkv, kvws);
        rope_k<<<dim3((M_TOT * 128) / 256), 256, 0, stream>>>(kvws, freqs);
        attn_fused<<<dim3(NQ), 256, 0, stream>>>(query, qpos, Wq, Wout, gamma, beta,
                                                 freqs, kvws, out);
    }
}

// Round 6
// 222.951 us; speedup vs baseline: 1.6400x; 1.6400x over previous
//
#include <hip/hip_runtime.h>
#include <math.h>

// Problem constants (fixed by reference setup_inputs)
#define NQ    2048      // B*QB
#define Dd    256
#define NHh   8
#define HDd   32
#define KK    164       // 9+25+49+81
#define KP    192       // padded K (6 full 32-tiles)
#define PPB   5440      // valid cells per batch: 64+256+1024+4096
#define M_TOT 21760     // 4 * PPB
#define TWO_D 512

using bf16x8  = __attribute__((ext_vector_type(8))) short;
using f32x4   = __attribute__((ext_vector_type(4))) float;
using ushort8 = __attribute__((ext_vector_type(8))) unsigned short;

__device__ __forceinline__ unsigned short bf16_rne(float x) {
    unsigned u = __float_as_uint(x);
    return (unsigned short)((u + 0x7fffu + ((u >> 16) & 1u)) >> 16);
}
__device__ __forceinline__ float bf2f(unsigned short h) {
    return __uint_as_float((unsigned)h << 16);
}

__device__ __forceinline__ void gload_lds16(const void* g, void* s) {
    __builtin_amdgcn_global_load_lds(
        (const __attribute__((address_space(1))) void*)g,
        (__attribute__((address_space(3))) void*)s, 16, 0, 0);
}

__device__ __forceinline__ void row_geom(int r, int& l, int& S, int& base, int& lg, int& inv) {
    if      (r < 64)   { l = 0; S = 8;  base = 0;    lg = 3; inv = 8; }
    else if (r < 320)  { l = 1; S = 16; base = 64;   lg = 4; inv = 4; }
    else if (r < 1344) { l = 2; S = 32; base = 320;  lg = 5; inv = 2; }
    else               { l = 3; S = 64; base = 1344; lg = 6; inv = 1; }
}

// ---------------------------------------------------------------------------
// gather valid cells, split fp32 -> bf16 hi/lo, compacted [m][k=256]
// ---------------------------------------------------------------------------
__global__ __launch_bounds__(256) void gather_split(const float* __restrict__ fmap,
                                                    unsigned short* __restrict__ Ahi,
                                                    unsigned short* __restrict__ Alo) {
    int gid = blockIdx.x * 256 + threadIdx.x;
    int m = gid >> 6, c4 = (gid & 63) << 2;
    int b = m / PPB, r = m - b * PPB;
    int l, S, base, lg, inv;
    row_geom(r, l, S, base, lg, inv);
    int idx = r - base;
    int i = idx >> lg, j = idx & (S - 1);
    size_t rowOff = ((size_t)((b * 64 + i) * 64 + j)) * 1024 + l * 256;
    const float4 v = *(const float4*)(fmap + rowOff + c4);
    ushort4 hi, lo;
    hi.x = bf16_rne(v.x); lo.x = bf16_rne(v.x - __uint_as_float((unsigned)hi.x << 16));
    hi.y = bf16_rne(v.y); lo.y = bf16_rne(v.y - __uint_as_float((unsigned)hi.y << 16));
    hi.z = bf16_rne(v.z); lo.z = bf16_rne(v.z - __uint_as_float((unsigned)hi.z << 16));
    hi.w = bf16_rne(v.w); lo.w = bf16_rne(v.w - __uint_as_float((unsigned)hi.w << 16));
    *(ushort4*)(Ahi + (size_t)m * 256 + c4) = hi;
    *(ushort4*)(Alo + (size_t)m * 256 + c4) = lo;
}

// ---------------------------------------------------------------------------
// W (256 x N, row-major over k) -> Bt hi/lo transposed [n][k=256]
// ---------------------------------------------------------------------------
__global__ __launch_bounds__(256) void splitw_t(const float* __restrict__ W,
                                                unsigned short* __restrict__ Bthi,
                                                unsigned short* __restrict__ Btlo,
                                                int N) {
    int gid = blockIdx.x * 256 + threadIdx.x;
    int k = gid & 255, n = gid >> 8;
    float x = W[k * N + n];
    unsigned short h = bf16_rne(x);
    unsigned short lo = bf16_rne(x - __uint_as_float((unsigned)h << 16));
    Bthi[n * 256 + k] = h;
    Btlo[n * 256 + k] = lo;
}

// ---------------------------------------------------------------------------
// KV = A @ Wkv via split-bf16 MFMA (M=21760, N=512, K=256, 3 segments).
// OUTPUT IS bf16 ([m][512] ushort): epilogue pairs adjacent columns via
// shfl_xor and stores packed 4B words from even lanes.
// ---------------------------------------------------------------------------
__global__ __launch_bounds__(256) void kv_gemm_mfma(const unsigned short* __restrict__ Ahi,
                                                    const unsigned short* __restrict__ Alo,
                                                    const unsigned short* __restrict__ Bthi,
                                                    const unsigned short* __restrict__ Btlo,
                                                    unsigned short* __restrict__ kv16) {
    __shared__ __align__(16) short As[2][128 * 32];
    __shared__ __align__(16) short Bs[2][128 * 32];

    const int t  = threadIdx.x;
    const int w  = t >> 6, l = t & 63;
    const int wr = w >> 1, wc = w & 1;
    const int bm = blockIdx.x * 128, n0 = blockIdx.y * 128;
    const int lr = l & 15, ks = l >> 4;
    const int ksw8 = ((ks ^ ((lr >> 1) & 3)) << 3);

    f32x4 acc[4][4];
#pragma unroll
    for (int i = 0; i < 4; i++)
#pragma unroll
        for (int j = 0; j < 4; j++) { f32x4 z = {0.f,0.f,0.f,0.f}; acc[i][j] = z; }

    const int srow = l >> 2, sslot = l & 3;
    const int gs = sslot ^ ((srow >> 1) & 3);

    auto stage = [&](int kt, int buf) {
        int seg = kt >> 3;
        const unsigned short* Aseg = (seg < 2) ? Ahi : Alo;
        const unsigned short* Bseg = (seg == 1) ? Btlo : Bthi;
        size_t k0b = (size_t)((kt & 7) << 6);
#pragma unroll
        for (int i = 0; i < 2; i++) {
            int rb = w * 32 + i * 16;
            int m  = rb + srow;
            gload_lds16((const char*)Aseg + (((size_t)(bm + m)) << 9) + k0b + (gs << 4),
                        (void*)&As[buf][rb * 32]);
            gload_lds16((const char*)Bseg + (((size_t)(n0 + m)) << 9) + k0b + (gs << 4),
                        (void*)&Bs[buf][rb * 32]);
        }
    };

    stage(0, 0);
    __syncthreads();

    for (int kt = 0; kt < 24; kt++) {
        int cur = kt & 1;
        if (kt < 23) stage(kt + 1, cur ^ 1);

        bf16x8 afr[4], bfr[4];
#pragma unroll
        for (int f = 0; f < 4; f++) {
            int m = wr * 64 + f * 16 + lr;
            afr[f] = *(const bf16x8*)&As[cur][m * 32 + ksw8];
            int n = wc * 64 + f * 16 + lr;
            bfr[f] = *(const bf16x8*)&Bs[cur][n * 32 + ksw8];
        }
#pragma unroll
        for (int i = 0; i < 4; i++)
#pragma unroll
            for (int j = 0; j < 4; j++)
                acc[i][j] = __builtin_amdgcn_mfma_f32_16x16x32_bf16(afr[i], bfr[j],
                                                                    acc[i][j], 0, 0, 0);
        __syncthreads();
    }

    // epilogue: C/D layout col = lane&15, row = (lane>>4)*4 + reg.
    // lanes lr and lr^1 hold adjacent columns -> pack 2 bf16, even lane stores.
#pragma unroll
    for (int i = 0; i < 4; i++) {
        int mg = bm + wr * 64 + i * 16 + ks * 4;
#pragma unroll
        for (int j = 0; j < 4; j++) {
            int ng = n0 + wc * 64 + j * 16 + lr;
#pragma unroll
            for (int r = 0; r < 4; r++) {
                float self = acc[i][j][r];
                float part = __shfl_xor(self, 1);
                if (!(lr & 1)) {
                    unsigned word = (unsigned)bf16_rne(self)
                                  | ((unsigned)bf16_rne(part) << 16);
                    *(unsigned*)(kv16 + (size_t)(mg + r) * TWO_D + ng) = word;
                }
            }
        }
    }
}

// ---------------------------------------------------------------------------
// proj GEMM: C(2048x256) = A(2048x256) @ W(256x256) [+resid], split-bf16 MFMA
// ---------------------------------------------------------------------------
template<bool RESID>
__global__ __launch_bounds__(256) void proj_gemm(const unsigned short* __restrict__ Ahi,
                                                 const unsigned short* __restrict__ Alo,
                                                 const unsigned short* __restrict__ Bthi,
                                                 const unsigned short* __restrict__ Btlo,
                                                 float* __restrict__ C,
                                                 const float* __restrict__ resid) {
    __shared__ __align__(16) short As[2][128 * 32];
    __shared__ __align__(16) short Bs[2][64 * 32];

    const int t  = threadIdx.x;
    const int w  = t >> 6, l = t & 63;
    const int bm = blockIdx.x * 128, n0 = blockIdx.y * 64;
    const int lr = l & 15, ks = l >> 4;
    const int ksw8 = ((ks ^ ((lr >> 1) & 3)) << 3);

    f32x4 acc[2][4];
#pragma unroll
    for (int i = 0; i < 2; i++)
#pragma unroll
        for (int j = 0; j < 4; j++) { f32x4 z = {0.f,0.f,0.f,0.f}; acc[i][j] = z; }

    const int srow = l >> 2, sslot = l & 3;
    const int gs = sslot ^ ((srow >> 1) & 3);

    auto stage = [&](int kt, int buf) {
        int seg = kt >> 3;
        const unsigned short* Aseg = (seg < 2) ? Ahi : Alo;
        const unsigned short* Bseg = (seg == 1) ? Btlo : Bthi;
        size_t k0b = (size_t)((kt & 7) << 6);
#pragma unroll
        for (int i = 0; i < 2; i++) {
            int rb = w * 32 + i * 16;
            int m  = rb + srow;
            gload_lds16((const char*)Aseg + (((size_t)(bm + m)) << 9) + k0b + (gs << 4),
                        (void*)&As[buf][rb * 32]);
        }
        {
            int rb = w * 16;
            int m  = rb + srow;
            gload_lds16((const char*)Bseg + (((size_t)(n0 + m)) << 9) + k0b + (gs << 4),
                        (void*)&Bs[buf][rb * 32]);
        }
    };

    stage(0, 0);
    __syncthreads();

    for (int kt = 0; kt < 24; kt++) {
        int cur = kt & 1;
        if (kt < 23) stage(kt + 1, cur ^ 1);

        bf16x8 afr[2], bfr[4];
#pragma unroll
        for (int f = 0; f < 2; f++) {
            int m = w * 32 + f * 16 + lr;
            afr[f] = *(const bf16x8*)&As[cur][m * 32 + ksw8];
        }
#pragma unroll
        for (int j = 0; j < 4; j++) {
            int n = j * 16 + lr;
            bfr[j] = *(const bf16x8*)&Bs[cur][n * 32 + ksw8];
        }
#pragma unroll
        for (int i = 0; i < 2; i++)
#pragma unroll
            for (int j = 0; j < 4; j++)
                acc[i][j] = __builtin_amdgcn_mfma_f32_16x16x32_bf16(afr[i], bfr[j],
                                                                    acc[i][j], 0, 0, 0);
        __syncthreads();
    }

#pragma unroll
    for (int i = 0; i < 2; i++) {
        int mg = bm + w * 32 + i * 16 + ks * 4;
#pragma unroll
        for (int j = 0; j < 4; j++) {
            int ng = n0 + j * 16 + lr;
#pragma unroll
            for (int r = 0; r < 4; r++) {
                float v = acc[i][j][r];
                if (RESID) v += resid[(size_t)(mg + r) * 256 + ng];
                C[(size_t)(mg + r) * 256 + ng] = v;
            }
        }
    }
}

// ---------------------------------------------------------------------------
// in-place RoPE on the K half of kv16 (bf16 pairs)
// ---------------------------------------------------------------------------
__global__ __launch_bounds__(256) void rope_k(unsigned short* __restrict__ kv16,
                                              const float* __restrict__ freqs) {
    int gid = blockIdx.x * 256 + threadIdx.x;   // M_TOT * 128 pair-slots
    int m = gid >> 7;
    int p = gid & 127;
    int f = p & 15;

    int b = m / PPB;
    int r = m - b * PPB;
    int l, S, base, lg, inv;
    row_geom(r, l, S, base, lg, inv);
    int idx = r - base;
    int i = idx >> lg;
    int j = idx & (S - 1);

    float px = (float)(i * inv), py = (float)(j * inv), pl = (float)l;
    float ang = px * freqs[f] + py * freqs[16 + f] + pl * freqs[32 + f];
    float c = cosf(ang), s = sinf(ang);

    unsigned* kp = (unsigned*)kv16 + (size_t)m * 256 + p;  // K half = first 128 words
    unsigned v = *kp;
    float x1 = bf2f((unsigned short)(v & 0xffff));
    float x2 = bf2f((unsigned short)(v >> 16));
    float y1 = x1 * c - x2 * s;
    float y2 = x1 * s + x2 * c;
    *kp = (unsigned)bf16_rne(y1) | ((unsigned)bf16_rne(y2) << 16);
}

// ---------------------------------------------------------------------------
// LayerNorm + bf16 hi/lo split
// ---------------------------------------------------------------------------
__global__ __launch_bounds__(256) void ln_split(const float* __restrict__ query,
                                                const float* __restrict__ gamma,
                                                const float* __restrict__ beta,
                                                unsigned short* __restrict__ Xhi,
                                                unsigned short* __restrict__ Xlo) {
    __shared__ float red[4];
    const int q = blockIdx.x, t = threadIdx.x, wid = t >> 6;

    float x = query[q * Dd + t];
    float s = x;
#pragma unroll
    for (int mK = 32; mK >= 1; mK >>= 1) s += __shfl_xor(s, mK);
    if ((t & 63) == 0) red[wid] = s;
    __syncthreads();
    float mu = (red[0] + red[1] + red[2] + red[3]) * (1.0f / 256.0f);
    float dx = x - mu;
    float s2 = dx * dx;
#pragma unroll
    for (int mK = 32; mK >= 1; mK >>= 1) s2 += __shfl_xor(s2, mK);
    __syncthreads();
    if ((t & 63) == 0) red[wid] = s2;
    __syncthreads();
    float var = (red[0] + red[1] + red[2] + red[3]) * (1.0f / 256.0f);
    float v = dx * rsqrtf(var + 1e-5f) * gamma[t] + beta[t];
    unsigned short hi = bf16_rne(v);
    Xhi[q * Dd + t] = hi;
    Xlo[q * Dd + t] = bf16_rne(v - __uint_as_float((unsigned)hi << 16));
}

// ---------------------------------------------------------------------------
// attention core v3: RoPE(q) + scores -> softmax -> PV, bf16 KV.
// XCD-cluster swizzle: q = (bid&7)*256 + bid>>3  (contiguous half-batch/XCD).
// ---------------------------------------------------------------------------
__global__ __launch_bounds__(256) void attn_core(const float* __restrict__ qr,
                                                 const float* __restrict__ qpos,
                                                 const unsigned short* __restrict__ kv16,
                                                 const float* __restrict__ freqs,
                                                 unsigned short* __restrict__ Phi,
                                                 unsigned short* __restrict__ Plo) {
    __shared__ __align__(16) float qsh[Dd];
    __shared__ float sL[NHh * KP];
    __shared__ int   kidx[KP];
    __shared__ float attnP[8][Dd];
    __shared__ float invS[NHh];

    const int q = ((blockIdx.x & 7) << 8) | (blockIdx.x >> 3);
    const int t = threadIdx.x;
    const int h = t >> 5, lane = t & 31;

    float qx = qpos[q * 4 + 1];
    float qy = qpos[q * 4 + 2];
    int   bb = (int)qpos[q * 4 + 0];

    // ---- load q row + RoPE in-register (pairs are adjacent lanes) ----
    {
        float x = qr[q * Dd + t];
        int f = (t & 31) >> 1;
        float ang = qx * freqs[f] + qy * freqs[16 + f] + 3.0f * freqs[32 + f];
        float c = cosf(ang), sn = sinf(ang);
        float partner = __shfl_xor(x, 1);
        qsh[t] = (!(t & 1)) ? (x * c - partner * sn) : (partner * sn + x * c);
    }

    if (t < KP) {
        int k = t;
        int kv = -1;
        if (k < KK) {
            int S, base, off, sz, half, lg;
            if      (k < 9)  { S = 8;  base = 0;    off = k;      sz = 3; half = 1; lg = 3; }
            else if (k < 34) { S = 16; base = 64;   off = k - 9;  sz = 5; half = 2; lg = 4; }
            else if (k < 83) { S = 32; base = 320;  off = k - 34; sz = 7; half = 3; lg = 5; }
            else             { S = 64; base = 1344; off = k - 83; sz = 9; half = 4; lg = 6; }
            int di = off / sz - half;
            int dj = off % sz - half;
            float scal = (float)S * (1.0f / 64.0f);
            int ci = (int)floorf(qx * scal);
            int cj = (int)floorf(qy * scal);
            int i = ci + di, j = cj + dj;
            bool valid = (i >= 0) & (i < S) & (j >= 0) & (j < S);
            kv = valid ? (bb * PPB + base + (i << lg) + j) : -1;
        }
        kidx[t] = kv;
    }
    __syncthreads();

    // ---- scores: thread (h, lane) owns 6 k's; K rows are bf16 ----
    float qreg[32];
#pragma unroll
    for (int i = 0; i < 32; i++) qreg[i] = qsh[h * HDd + i];

#pragma unroll
    for (int ct = 0; ct < 6; ++ct) {
        int k = ct * 32 + lane;
        int ki = kidx[k];
        int kr = ki < 0 ? 0 : ki;
        const ushort8* kp = (const ushort8*)(kv16 + (size_t)kr * TWO_D + h * HDd);
        float c0 = 0.f, c1 = 0.f;
#pragma unroll
        for (int s4 = 0; s4 < 4; s4++) {
            ushort8 kvv = kp[s4];
            float* cc = (s4 & 1) ? &c1 : &c0;
#pragma unroll
            for (int e = 0; e < 8; e++)
                *cc = fmaf(qreg[s4 * 8 + e], bf2f(kvv[e]), *cc);
        }
        sL[h * KP + k] = (ki >= 0) ? (c0 + c1) : -INFINITY;
    }
    __syncthreads();

    // ---- softmax per head ----
    float mx = -INFINITY;
#pragma unroll
    for (int ct = 0; ct < 6; ++ct) mx = fmaxf(mx, sL[h * KP + ct * 32 + lane]);
#pragma unroll
    for (int mK = 16; mK >= 1; mK >>= 1) mx = fmaxf(mx, __shfl_xor(mx, mK));
    float se = 0.f;
#pragma unroll
    for (int ct = 0; ct < 6; ++ct) {
        int k = ct * 32 + lane;
        float e = __expf(sL[h * KP + k] - mx);
        sL[h * KP + k] = e;
        se += e;
    }
#pragma unroll
    for (int mK = 16; mK >= 1; mK >>= 1) se += __shfl_xor(se, mK);
    if (lane == 0) invS[h] = 1.0f / se;
    __syncthreads();

    // ---- PV: half-wave reads full 512B bf16 V row; 2 rows in flight/wave ----
    {
        const int rep  = t >> 6;          // wave: k-chunk of 48
        const int half = (t >> 5) & 1;    // which k within the pair
        const int l5   = t & 31;
        const int hh   = l5 >> 2;         // head
        const int oct  = l5 & 3;          // 8-dim octet within head
        float a[8];
#pragma unroll
        for (int e = 0; e < 8; e++) a[e] = 0.f;
        const unsigned short* vbase = kv16 + Dd + hh * HDd + oct * 8;
#pragma unroll 4
        for (int it = 0; it < 24; it++) {
            int k = rep * 48 + it * 2 + half;
            float w0 = sL[hh * KP + k];
            int kr = kidx[k]; kr = kr < 0 ? 0 : kr;
            ushort8 vv = *(const ushort8*)(vbase + (size_t)kr * TWO_D);
#pragma unroll
            for (int e = 0; e < 8; e++) a[e] = fmaf(w0, bf2f(vv[e]), a[e]);
        }
        float* dst = &attnP[t >> 5][hh * HDd + oct * 8];
#pragma unroll
        for (int e = 0; e < 8; e++) dst[e] = a[e];
    }
    __syncthreads();

    // ---- reduce 8 half-wave partials, scale, write bf16 hi/lo ----
    float val = 0.f;
#pragma unroll
    for (int s = 0; s < 8; s++) val += attnP[s][t];
    val *= invS[h];
    unsigned short hi = bf16_rne(val);
    Phi[q * Dd + t] = hi;
    Plo[q * Dd + t] = bf16_rne(val - __uint_as_float((unsigned)hi << 16));
}

// ---------------------------------------------------------------------------
// Fallback: fp32 pipeline (round-1 versions) if ws too small
// ---------------------------------------------------------------------------
#define BMf 128
#define BNf 128
#define KTf 16

__global__ __launch_bounds__(256) void kv_gemm(const float* __restrict__ fmap,
                                               const float* __restrict__ Wkv,
                                               float* __restrict__ kvws) {
    __shared__ float Asf[KTf][BMf + 4];
    __shared__ float Bsf[KTf][BNf + 4];
    __shared__ int   rowOff[BMf];

    const int t  = threadIdx.x;
    const int bm = blockIdx.x * BMf;
    const int n0 = blockIdx.y * BNf;

    if (t < BMf) {
        int m = bm + t;
        int b = m / PPB;
        int r = m - b * PPB;
        int l, S, base, lg, inv;
        row_geom(r, l, S, base, lg, inv);
        int idx = r - base;
        int i = idx >> lg;
        int j = idx & (S - 1);
        rowOff[t] = ((b * 64 + i) * 64 + j) * 1024 + l * 256;
    }
    __syncthreads();

    const int tx = t & 15, ty = t >> 4;
    float acc[8][8];
#pragma unroll
    for (int i = 0; i < 8; i++)
#pragma unroll
        for (int j = 0; j < 8; j++) acc[i][j] = 0.f;

    for (int k0 = 0; k0 < Dd; k0 += KTf) {
#pragma unroll
        for (int s = 0; s < 2; s++) {
            int task = t + s * 256;
            int row  = task >> 2;
            int k4   = (task & 3) * 4;
            const float4 v = *(const float4*)(fmap + rowOff[row] + k0 + k4);
            Asf[k4 + 0][row] = v.x;
            Asf[k4 + 1][row] = v.y;
            Asf[k4 + 2][row] = v.z;
            Asf[k4 + 3][row] = v.w;
        }
#pragma unroll
        for (int s = 0; s < 2; s++) {
            int task = t + s * 256;
            int kk   = task >> 5;
            int c4   = (task & 31) * 4;
            *(float4*)(&Bsf[kk][c4]) = *(const float4*)(Wkv + (k0 + kk) * TWO_D + n0 + c4);
        }
        __syncthreads();
#pragma unroll
        for (int kk = 0; kk < KTf; kk++) {
            float a[8], bb[8];
#pragma unroll
            for (int i = 0; i < 8; i++) a[i]  = Asf[kk][ty * 8 + i];
#pragma unroll
            for (int j = 0; j < 8; j++) bb[j] = Bsf[kk][tx * 8 + j];
#pragma unroll
            for (int i = 0; i < 8; i++)
#pragma unroll
                for (int j = 0; j < 8; j++)
                    acc[i][j] = fmaf(a[i], bb[j], acc[i][j]);
        }
        __syncthreads();
    }

#pragma unroll
    for (int i = 0; i < 8; i++) {
        int m = bm + ty * 8 + i;
        float* dst = kvws + (size_t)m * TWO_D + n0 + tx * 8;
#pragma unroll
        for (int j = 0; j < 8; j += 4) {
            *(float4*)(dst + j) = make_float4(acc[i][j], acc[i][j + 1],
                                              acc[i][j + 2], acc[i][j + 3]);
        }
    }
}

__global__ __launch_bounds__(256) void rope_k_f32(float* __restrict__ kvws,
                                                  const float* __restrict__ freqs) {
    int gid = blockIdx.x * 256 + threadIdx.x;
    int m = gid >> 7;
    int p = gid & 127;
    int f = p & 15;
    int b = m / PPB;
    int r = m - b * PPB;
    int l, S, base, lg, inv;
    row_geom(r, l, S, base, lg, inv);
    int idx = r - base;
    int i = idx >> lg;
    int j = idx & (S - 1);
    float px = (float)(i * inv), py = (float)(j * inv), pl = (float)l;
    float ang = px * freqs[f] + py * freqs[16 + f] + pl * freqs[32 + f];
    float c = cosf(ang), s = sinf(ang);
    float2* kp = (float2*)kvws + (size_t)m * 256 + p;
    float2 v = *kp;
    *kp = make_float2(v.x * c - v.y * s, v.x * s + v.y * c);
}

__global__ __launch_bounds__(256) void attn_fused(const float* __restrict__ query,
                                                  const float* __restrict__ qpos,
                                                  const float* __restrict__ Wq,
                                                  const float* __restrict__ Wout,
                                                  const float* __restrict__ gamma,
                                                  const float* __restrict__ beta,
                                                  const float* __restrict__ freqs,
                                                  const float* __restrict__ kvws,
                                                  float* __restrict__ out) {
    __shared__ float qn[Dd];
    __shared__ __align__(16) float qsh[Dd];
    __shared__ float sL[NHh * KK];
    __shared__ int   kidx[KK];
    __shared__ float attnL[Dd];
    __shared__ float red[4];
    __shared__ float invS[NHh];

    const int q = blockIdx.x;
    const int t = threadIdx.x;
    const int wid = t >> 6;
    const int h = t >> 5, lane = t & 31;

    float x = query[q * Dd + t];
    float s = x;
#pragma unroll
    for (int mK = 32; mK >= 1; mK >>= 1) s += __shfl_xor(s, mK);
    if ((t & 63) == 0) red[wid] = s;
    __syncthreads();
    float mu = (red[0] + red[1] + red[2] + red[3]) * (1.0f / 256.0f);
    float dx = x - mu;
    float s2 = dx * dx;
#pragma unroll
    for (int mK = 32; mK >= 1; mK >>= 1) s2 += __shfl_xor(s2, mK);
    __syncthreads();
    if ((t & 63) == 0) red[wid] = s2;
    __syncthreads();
    float var = (red[0] + red[1] + red[2] + red[3]) * (1.0f / 256.0f);
    float rs = rsqrtf(var + 1e-5f);
    qn[t] = dx * rs * gamma[t] + beta[t];
    __syncthreads();

    float a0 = 0.f, a1 = 0.f, a2 = 0.f, a3 = 0.f;
#pragma unroll 8
    for (int d = 0; d < Dd; d += 4) {
        a0 = fmaf(qn[d + 0], Wq[(d + 0) * Dd + t], a0);
        a1 = fmaf(qn[d + 1], Wq[(d + 1) * Dd + t], a1);
        a2 = fmaf(qn[d + 2], Wq[(d + 2) * Dd + t], a2);
        a3 = fmaf(qn[d + 3], Wq[(d + 3) * Dd + t], a3);
    }
    float acc = (a0 + a1) + (a2 + a3);

    float qx = qpos[q * 4 + 1];
    float qy = qpos[q * 4 + 2];
    int   bb = (int)qpos[q * 4 + 0];
    {
        int f = (t & 31) >> 1;
        float ang = qx * freqs[f] + qy * freqs[16 + f] + 3.0f * freqs[32 + f];
        float c = cosf(ang), sn = sinf(ang);
        float partner = __shfl_xor(acc, 1);
        bool ev = !(t & 1);
        acc = ev ? (acc * c - partner * sn) : (partner * sn + acc * c);
    }
    qsh[t] = acc;

    if (t < KK) {
        int k = t;
        int S, base, off, sz, half, lg;
        if      (k < 9)  { S = 8;  base = 0;    off = k;      sz = 3; half = 1; lg = 3; }
        else if (k < 34) { S = 16; base = 64;   off = k - 9;  sz = 5; half = 2; lg = 4; }
        else if (k < 83) { S = 32; base = 320;  off = k - 34; sz = 7; half = 3; lg = 5; }
        else             { S = 64; base = 1344; off = k - 83; sz = 9; half = 4; lg = 6; }
        int di = off / sz - half;
        int dj = off % sz - half;
        float scal = (float)S * (1.0f / 64.0f);
        int ci = (int)floorf(qx * scal);
        int cj = (int)floorf(qy * scal);
        int i = ci + di, j = cj + dj;
        bool valid = (i >= 0) & (i < S) & (j >= 0) & (j < S);
        kidx[t] = valid ? (bb * PPB + base + (i << lg) + j) : -1;
    }
    __syncthreads();

    float4 qv[8];
    {
        const float4* qp = (const float4*)(qsh + h * HDd);
#pragma unroll
        for (int i = 0; i < 8; i++) qv[i] = qp[i];
    }
#pragma unroll
    for (int ct = 0; ct < 6; ++ct) {
        int k = ct * 32 + lane;
        if (k >= KK) break;
        int ki = kidx[k];
        int kr = ki < 0 ? 0 : ki;
        const float4* kp = (const float4*)(kvws + (size_t)kr * TWO_D + h * HDd);
        float c0 = 0.f, c1 = 0.f;
#pragma unroll
        for (int i = 0; i < 8; i += 2) {
            float4 k0v = kp[i], k1v = kp[i + 1];
            c0 = fmaf(qv[i].x, k0v.x, c0); c0 = fmaf(qv[i].y, k0v.y, c0);
            c0 = fmaf(qv[i].z, k0v.z, c0); c0 = fmaf(qv[i].w, k0v.w, c0);
            c1 = fmaf(qv[i + 1].x, k1v.x, c1); c1 = fmaf(qv[i + 1].y, k1v.y, c1);
            c1 = fmaf(qv[i + 1].z, k1v.z, c1); c1 = fmaf(qv[i + 1].w, k1v.w, c1);
        }
        sL[h * KK + k] = (ki >= 0) ? (c0 + c1) : -INFINITY;
    }
    __syncthreads();

    float mx = -INFINITY;
    for (int k = lane; k < KK; k += 32) mx = fmaxf(mx, sL[h * KK + k]);
#pragma unroll
    for (int mK = 16; mK >= 1; mK >>= 1) mx = fmaxf(mx, __shfl_xor(mx, mK));
    float se = 0.f;
    for (int k = lane; k < KK; k += 32) {
        float e = expf(sL[h * KK + k] - mx);
        sL[h * KK + k] = e;
        se += e;
    }
#pragma unroll
    for (int mK = 16; mK >= 1; mK >>= 1) se += __shfl_xor(se, mK);
    if (lane == 0) invS[h] = 1.0f / se;
    __syncthreads();

    float p0 = 0.f, p1 = 0.f, p2 = 0.f, p3 = 0.f;
#pragma unroll 4
    for (int k = 0; k < 164; k += 4) {
        int ki0 = kidx[k],     kr0 = ki0 < 0 ? 0 : ki0;
        int ki1 = kidx[k + 1], kr1 = ki1 < 0 ? 0 : ki1;
        int ki2 = kidx[k + 2], kr2 = ki2 < 0 ? 0 : ki2;
        int ki3 = kidx[k + 3], kr3 = ki3 < 0 ? 0 : ki3;
        p0 = fmaf(sL[h * KK + k],     kvws[(size_t)kr0 * TWO_D + Dd + t], p0);
        p1 = fmaf(sL[h * KK + k + 1], kvws[(size_t)kr1 * TWO_D + Dd + t], p1);
        p2 = fmaf(sL[h * KK + k + 2], kvws[(size_t)kr2 * TWO_D + Dd + t], p2);
        p3 = fmaf(sL[h * KK + k + 3], kvws[(size_t)kr3 * TWO_D + Dd + t], p3);
    }
    attnL[t] = ((p0 + p1) + (p2 + p3)) * invS[h];
    __syncthreads();

    float o0 = query[q * Dd + t], o1 = 0.f, o2 = 0.f, o3 = 0.f;
#pragma unroll 8
    for (int d = 0; d < Dd; d += 4) {
        o0 = fmaf(attnL[d + 0], Wout[(d + 0) * Dd + t], o0);
        o1 = fmaf(attnL[d + 1], Wout[(d + 1) * Dd + t], o1);
        o2 = fmaf(attnL[d + 2], Wout[(d + 2) * Dd + t], o2);
        o3 = fmaf(attnL[d + 3], Wout[(d + 3) * Dd + t], o3);
    }
    out[q * Dd + t] = (o0 + o1) + (o2 + o3);
}

// ---------------------------------------------------------------------------
extern "C" void kernel_launch(void* const* d_in, const int* in_sizes, int n_in,
                              void* d_out, int out_size, void* d_ws, size_t ws_size,
                              hipStream_t stream) {
    const float* query = (const float*)d_in[0];
    const float* qpos  = (const float*)d_in[1];
    const float* fmap  = (const float*)d_in[3];
    const float* gamma = (const float*)d_in[5];
    const float* beta  = (const float*)d_in[6];
    const float* Wq    = (const float*)d_in[7];
    const float* Wkv   = (const float*)d_in[8];
    const float* Wout  = (const float*)d_in[9];
    const float* freqs = (const float*)d_in[10];
    float* out = (float*)d_out;

    const size_t KV_B = (size_t)M_TOT * TWO_D * 4;   // keep round-3-proven layout
    const size_t A_B  = (size_t)M_TOT * Dd * 2;
    const size_t WT_B = (size_t)Dd * TWO_D * 2;
    const size_t need = KV_B + 2 * A_B + 2 * WT_B;   // 67,371,008

    if (ws_size >= need) {
        char* base = (char*)d_ws;
        unsigned short* kv16   = (unsigned short*)base;                       // 22.3MB used
        unsigned short* Ahi    = (unsigned short*)(base + KV_B);
        unsigned short* Alo    = (unsigned short*)(base + KV_B + A_B);
        unsigned short* WkvThi = (unsigned short*)(base + KV_B + 2 * A_B);
        unsigned short* WkvTlo = (unsigned short*)(base + KV_B + 2 * A_B + WT_B);
        // overlay inside the Ahi region (dead after kv_gemm_mfma):
        unsigned short* Phi    = (unsigned short*)(base + KV_B);              // also Xhi
        unsigned short* Plo    = (unsigned short*)(base + KV_B + 1048576);    // also Xlo
        float*          qrw    = (float*)        (base + KV_B + 2097152);
        unsigned short* WqThi  = (unsigned short*)(base + KV_B + 4194304);
        unsigned short* WqTlo  = (unsigned short*)(base + KV_B + 4325376);
        unsigned short* WoThi  = (unsigned short*)(base + KV_B + 4456448);
        unsigned short* WoTlo  = (unsigned short*)(base + KV_B + 4587520);

        gather_split<<<dim3((M_TOT * 64) / 256), 256, 0, stream>>>(fmap, Ahi, Alo);
        splitw_t<<<dim3(512), 256, 0, stream>>>(Wkv, WkvThi, WkvTlo, 512);
        kv_gemm_mfma<<<dim3(M_TOT / 128, 4), 256, 0, stream>>>(Ahi, Alo, WkvThi, WkvTlo, kv16);
        rope_k<<<dim3((M_TOT * 128) / 256), 256, 0, stream>>>(kv16, freqs);
        // Ahi/Alo now dead -> overlay region usable
        ln_split<<<dim3(NQ), 256, 0, stream>>>(query, gamma, beta, Phi, Plo);
        splitw_t<<<dim3(256), 256, 0, stream>>>(Wq, WqThi, WqTlo, 256);
        splitw_t<<<dim3(256), 256, 0, stream>>>(Wout, WoThi, WoTlo, 256);
        proj_gemm<false><<<dim3(NQ / 128, 4), 256, 0, stream>>>(Phi, Plo, WqThi, WqTlo,
                                                                qrw, nullptr);
        attn_core<<<dim3(NQ), 256, 0, stream>>>(qrw, qpos, kv16, freqs, Phi, Plo);
        proj_gemm<true><<<dim3(NQ / 128, 4), 256, 0, stream>>>(Phi, Plo, WoThi, WoTlo,
                                                               out, query);
    } else {
        float* kvws = (float*)d_ws;
        kv_gemm<<<dim3(M_TOT / BMf, TWO_D / BNf), 256, 0, stream>>>(fmap, Wkv, kvws);
        rope_k_f32<<<dim3((M_TOT * 128) / 256), 256, 0, stream>>>(kvws, freqs);
        attn_fused<<<dim3(NQ), 256, 0, stream>>>(query, qpos, Wq, Wout, gamma, beta,
                                                 freqs, kvws, out);
    }
}